// Round 13
// baseline (78.338 us; speedup 1.0000x reference)
//
#include <hip/hip_runtime.h>

// Problem constants (fixed by the reference)
#define BATCH   8192
#define GROUPS  512
#define ARITY   3
#define OUT_DIM 16
#define NV      27          // 3^3 vertices
#define XCOLS   (GROUPS*ARITY)      // 1536
#define OCOLS   (GROUPS*OUT_DIM)    // 8192

// R13 = R11 (best, 60.0us) with ONE change: plain stores instead of
// nontemporal. R6/R7's "nt wins +10us" was measured in the BAD-locality
// regime (b-fast grid, 4 ragged rounds). After the axis swap + single
// residency round, the fill kernels' 6.9 TB/s (plain stores, L2
// write-combining) suggests the L2 path may beat the nt bypass here.
#define BTILE 32
#define NCHUNK 4
#define GTILE 16
#define PSTRIDE 444     // bf16 elems per group (432 + 12 pad)

typedef float    f32x4 __attribute__((ext_vector_type(4)));
typedef unsigned u32x2 __attribute__((ext_vector_type(2)));

__device__ __forceinline__ unsigned cvt_pk_bf16(float lo, float hi) {
    unsigned r;
    asm("v_cvt_pk_bf16_f32 %0, %1, %2" : "=v"(r) : "v"(lo), "v"(hi));
    return r;
}
__device__ __forceinline__ float bflo(unsigned u) {
    union { unsigned u; float f; } c; c.u = u << 16; return c.f;
}
__device__ __forceinline__ float bfhi(unsigned u) {
    union { unsigned u; float f; } c; c.u = u & 0xffff0000u; return c.f;
}

__global__ __launch_bounds__(256, 8) void lattice_interp_kernel(
    const float* __restrict__ X,
    const float* __restrict__ P,
    float* __restrict__ out)
{
    __shared__ float xs[BTILE * GTILE * ARITY];        // 1536 f32 = 6144 B
    __shared__ unsigned short ps[GTILE * PSTRIDE];     // 7104 bf16 = 14208 B

    const int t  = threadIdx.x;
    const int g0 = blockIdx.x * GTILE;              // group chunk: FAST dim
    const int bbase = blockIdx.y * (BTILE * NCHUNK); // 128-batch span: SLOW

    // ---- stage params for 16 groups as bf16 (ONCE per block):
    // 1728 float4 -> cvt_pk -> ds_write_b64. group pgl at elem pgl*444.
    {
        const float4* src = reinterpret_cast<const float4*>(P + (size_t)g0 * (NV * OUT_DIM));
        #pragma unroll
        for (int k = 0; k < 7; ++k) {
            const int f = t + k * 256;
            if (f < 1728) {
                const float4 v = src[f];
                const int pgl = f / 108;          // 108 float4 per group
                const int rem = f - pgl * 108;
                u32x2 w;
                w.x = cvt_pk_bf16(v.x, v.y);
                w.y = cvt_pk_bf16(v.z, v.w);
                *reinterpret_cast<u32x2*>(&ps[pgl * PSTRIDE + rem * 4]) = w;
            }
        }
    }

    // ---- stage X chunk 0: rows [bbase, bbase+32) cols [g0*3, g0*3+48).
    {
        const float* src_base = X + (size_t)bbase * XCOLS + g0 * ARITY;
        #pragma unroll
        for (int k = 0; k < 2; ++k) {
            const int f = t + k * 256;
            if (f < 384) {
                const int r = f / 12, c = f % 12;
                __builtin_amdgcn_global_load_lds(
                    (const __attribute__((address_space(1))) void*)(src_base + (size_t)r * XCOLS + c * 4),
                    (__attribute__((address_space(3))) void*)&xs[f * 4],
                    16, 0, 0);
            }
        }
    }

    __syncthreads();   // drains global_load_lds (vmcnt) + ds_writes (lgkmcnt)

    const int wv = t >> 6;
    const int l  = t & 63;
    const int gl = l >> 2;    // group-local 0..15
    const int oq = l & 3;     // which float4 of the 16 outputs

    const unsigned short* pbase = ps + gl * PSTRIDE + oq * 4;  // + vb*16 at runtime
    const float* xb = xs + gl * ARITY;

    #pragma unroll 1
    for (int j = 0; j < NCHUNK; ++j) {
        const int b0 = bbase + j * BTILE;
        // within-block out col = gl*16 + oq*4 = 4*l -> wave writes 1KB contiguous
        float* outp = out + (size_t)b0 * OCOLS + (size_t)g0 * OUT_DIM + l * 4;

        #pragma unroll 2
        for (int i = 0; i < 8; ++i) {
            const int b = wv * 8 + i;
            const float x0 = xb[b * (GTILE * ARITY) + 0];
            const float x1 = xb[b * (GTILE * ARITY) + 1];
            const float x2 = xb[b * (GTILE * ARITY) + 2];

            // containing cell per dim; lower/upper hat weights (3rd == 0)
            const bool n0 = x0 < 0.0f, n1 = x1 < 0.0f, n2 = x2 < 0.0f;
            const float wl0 = n0 ? -x0       : 1.0f - x0;
            const float wh0 = n0 ? 1.0f + x0 : x0;
            const float wl1 = n1 ? -x1       : 1.0f - x1;
            const float wh1 = n1 ? 1.0f + x1 : x1;
            const float wl2 = n2 ? -x2       : 1.0f - x2;
            const float wh2 = n2 ? 1.0f + x2 : x2;
            const int   vb  = (n0 ? 0 : 1) + 3 * (n1 ? 0 : 1) + 9 * (n2 ? 0 : 1);

            // 8 corner weights
            const float wA = wl0 * wl1, wB = wh0 * wl1, wC = wl0 * wh1, wD = wh0 * wh1;
            const float c000 = wA * wl2, c100 = wB * wl2, c010 = wC * wl2, c110 = wD * wl2;
            const float c001 = wA * wh2, c101 = wB * wh2, c011 = wC * wh2, c111 = wD * wh2;

            // one runtime base + 8 immediate-offset ds_read_b64 (4 bf16 each)
            const u32x2* pp = reinterpret_cast<const u32x2*>(pbase + (size_t)vb * 16);
            const u32x2 r0 = pp[0];        // dv=0  (c000)
            const u32x2 r1 = pp[4];        // dv=1  (c100)
            const u32x2 r2 = pp[12];       // dv=3  (c010)
            const u32x2 r3 = pp[16];       // dv=4  (c110)
            const u32x2 r4 = pp[36];       // dv=9  (c001)
            const u32x2 r5 = pp[40];       // dv=10 (c101)
            const u32x2 r6 = pp[48];       // dv=12 (c011)
            const u32x2 r7 = pp[52];       // dv=13 (c111)

            f32x4 acc;
            { f32x4 pv = { bflo(r0.x), bfhi(r0.x), bflo(r0.y), bfhi(r0.y) }; acc  = c000 * pv; }
            { f32x4 pv = { bflo(r1.x), bfhi(r1.x), bflo(r1.y), bfhi(r1.y) }; acc += c100 * pv; }
            { f32x4 pv = { bflo(r2.x), bfhi(r2.x), bflo(r2.y), bfhi(r2.y) }; acc += c010 * pv; }
            { f32x4 pv = { bflo(r3.x), bfhi(r3.x), bflo(r3.y), bfhi(r3.y) }; acc += c110 * pv; }
            { f32x4 pv = { bflo(r4.x), bfhi(r4.x), bflo(r4.y), bfhi(r4.y) }; acc += c001 * pv; }
            { f32x4 pv = { bflo(r5.x), bfhi(r5.x), bflo(r5.y), bfhi(r5.y) }; acc += c101 * pv; }
            { f32x4 pv = { bflo(r6.x), bfhi(r6.x), bflo(r6.y), bfhi(r6.y) }; acc += c011 * pv; }
            { f32x4 pv = { bflo(r7.x), bfhi(r7.x), bflo(r7.y), bfhi(r7.y) }; acc += c111 * pv; }

            *reinterpret_cast<f32x4*>(outp + (size_t)b * OCOLS) = acc;
        }

        __syncthreads();   // all waves done reading xs before restage

        if (j + 1 < NCHUNK) {
            const float* src_base = X + (size_t)(bbase + (j + 1) * BTILE) * XCOLS + g0 * ARITY;
            #pragma unroll
            for (int k = 0; k < 2; ++k) {
                const int f = t + k * 256;
                if (f < 384) {
                    const int r = f / 12, c = f % 12;
                    __builtin_amdgcn_global_load_lds(
                        (const __attribute__((address_space(1))) void*)(src_base + (size_t)r * XCOLS + c * 4),
                        (__attribute__((address_space(3))) void*)&xs[f * 4],
                        16, 0, 0);
                }
            }
            __syncthreads();   // staging complete before compute reads
        }
    }
}

extern "C" void kernel_launch(void* const* d_in, const int* in_sizes, int n_in,
                              void* d_out, int out_size, void* d_ws, size_t ws_size,
                              hipStream_t stream) {
    const float* X = (const float*)d_in[0];   // [8192, 1536] f32
    const float* P = (const float*)d_in[1];   // [512, 27, 16] f32
    float* out = (float*)d_out;               // [8192, 8192] f32

    dim3 grid(GROUPS / GTILE, BATCH / (BTILE * NCHUNK)); // 32 x 64 = 2048
    dim3 block(256);
    lattice_interp_kernel<<<grid, block, 0, stream>>>(X, P, out);
}